// Round 5
// baseline (77.122 us; speedup 1.0000x reference)
//
#include <hip/hip_runtime.h>
#include <stdint.h>

// ---------------------------------------------------------------------------
// GraphSAGE SampleAndAggregate (2-layer mean aggregator, concat=True)
//
// RNG: JAX threefry2x32. Variant ladder:
//   0 = no-x64 partitionable, NO internal randint split   [FAILED r1, 0.1475]
//   2 = no-x64 legacy,        NO internal randint split   [FAILED r2, 0.1323]
//   3 = x64 partitionable,    NO internal randint split   [FAILED r3, 0.1377]
//   4 = x64 legacy,           NO internal randint split   [FAILED r4, 0.1345]
//   5 = no-x64 partitionable, WITH randint's internal k1,k2=split(key);
//       col_i = fold(tf(tf(key,(0,1)), (0,i))) & 127       <-- this round
//   6 = no-x64 legacy, WITH internal split (odd/even iota pairing) [next]
// ---------------------------------------------------------------------------
#define JAX_RNG_VARIANT 5

#define N_NODES 100000
#define F_DIM   256
#define H_DIM   128
#define MAX_DEG 128
#define BATCH   512
#define S1N     25
#define S2N     10
#define NS1     (BATCH * S2N)   // 5120  (s1 sample count)
#define NS2     (NS1 * S1N)     // 128000 (s2 sample count)

__device__ __forceinline__ void tf2(uint32_t k0, uint32_t k1, uint32_t c0, uint32_t c1,
                                    uint32_t& o0, uint32_t& o1) {
  uint32_t ks0 = k0, ks1 = k1, ks2 = k0 ^ k1 ^ 0x1BD11BDAu;
  uint32_t x0 = c0 + ks0;
  uint32_t x1 = c1 + ks1;
  const uint32_t rotA[4] = {13u, 15u, 26u, 6u};
  const uint32_t rotB[4] = {17u, 29u, 16u, 24u};
#define TF_ROUND(r) { x0 += x1; x1 = (x1 << (r)) | (x1 >> (32 - (r))); x1 ^= x0; }
  TF_ROUND(rotA[0]); TF_ROUND(rotA[1]); TF_ROUND(rotA[2]); TF_ROUND(rotA[3]);
  x0 += ks1; x1 += ks2 + 1u;
  TF_ROUND(rotB[0]); TF_ROUND(rotB[1]); TF_ROUND(rotB[2]); TF_ROUND(rotB[3]);
  x0 += ks2; x1 += ks0 + 2u;
  TF_ROUND(rotA[0]); TF_ROUND(rotA[1]); TF_ROUND(rotA[2]); TF_ROUND(rotA[3]);
  x0 += ks0; x1 += ks1 + 3u;
  TF_ROUND(rotB[0]); TF_ROUND(rotB[1]); TF_ROUND(rotB[2]); TF_ROUND(rotB[3]);
  x0 += ks1; x1 += ks2 + 4u;
  TF_ROUND(rotA[0]); TF_ROUND(rotA[1]); TF_ROUND(rotA[2]); TF_ROUND(rotA[3]);
  x0 += ks2; x1 += ks0 + 5u;
#undef TF_ROUND
  o0 = x0; o1 = x1;
}

// subkey idx of jax.random.split(jax.random.key(42))
__device__ __forceinline__ void jax_subkey(int idx, uint32_t& k0, uint32_t& k1) {
#if JAX_RNG_VARIANT == 2 || JAX_RNG_VARIANT == 4 || JAX_RNG_VARIANT == 6
  // legacy split: threefry_2x32(key, iota(4)) -> pairs (0,2),(1,3)
  uint32_t a0, a1, b0, b1;
  tf2(0u, 42u, 0u, 2u, a0, a1);
  tf2(0u, 42u, 1u, 3u, b0, b1);
  if (idx == 0) { k0 = a0; k1 = b0; } else { k0 = a1; k1 = b1; }
#else
  // foldlike split: subkey i = cipher(key, (0, i))
  tf2(0u, 42u, 0u, (uint32_t)idx, k0, k1);
#endif
}

// column draw i of jax.random.randint(key, shape(size), 0, 128):
// span=128 pow2 -> multiplier=0 -> col = lower_bits % 128
__device__ __forceinline__ uint32_t jax_randcol(uint32_t k0, uint32_t k1,
                                                uint32_t i, uint32_t size) {
  uint32_t o0, o1;
#if JAX_RNG_VARIANT == 5
  // _randint does k1,k2 = split(key) internally; lower_bits = random_bits(k2,32,shape)
  // partitionable: k2 = tf(key,(0,1)); lower[i] = x0^x1 of tf(k2, (0,i))
  uint32_t kk0, kk1;
  tf2(k0, k1, 0u, 1u, kk0, kk1);
  tf2(kk0, kk1, 0u, i, o0, o1);
  return (o0 ^ o1) & (MAX_DEG - 1);
#elif JAX_RNG_VARIANT == 6
  // legacy internal split: k2 = (o1(tf(key,(0,2))), o1(tf(key,(1,3))));
  // bits = threefry_2x32(k2, iota(size)) with odd/even halving:
  //   i <  size/2: bits[i] = o0 of tf(k2, (i, size/2+i))
  //   i >= size/2: bits[i] = o1 of tf(k2, (i-size/2, i))
  uint32_t a0, a1, b0, b1;
  tf2(k0, k1, 0u, 2u, a0, a1);
  tf2(k0, k1, 1u, 3u, b0, b1);
  uint32_t kk0 = a1, kk1 = b1, h = size >> 1;
  if (i < h) { tf2(kk0, kk1, i, h + i, o0, o1); return o0 & (MAX_DEG - 1); }
  else       { tf2(kk0, kk1, i - h, i, o0, o1); return o1 & (MAX_DEG - 1); }
#elif JAX_RNG_VARIANT == 0
  tf2(k0, k1, 0u, size + i, o0, o1);
  return (o0 ^ o1) & (MAX_DEG - 1);
#elif JAX_RNG_VARIANT == 3
  tf2(k0, k1, 0u, size + i, o0, o1);
  return o1 & (MAX_DEG - 1);
#elif JAX_RNG_VARIANT == 4
  tf2(k0, k1, size + i, 3u * size + i, o0, o1);
  return o1 & (MAX_DEG - 1);
#else // 2
  tf2(k0, k1, i, size + i, o0, o1);
  return o1 & (MAX_DEG - 1);
#endif
}

// ---------------------------------------------------------------------------
// K1: s1[i] = adj[batch[i/10], col(k1, i)]
__global__ __launch_bounds__(256) void k_sample1(const int* __restrict__ adj,
                                                 const int* __restrict__ batch,
                                                 int* __restrict__ s1) {
  int i = blockIdx.x * 256 + threadIdx.x;
  if (i >= NS1) return;
  uint32_t k0, k1;
  jax_subkey(0, k0, k1);
  uint32_t col = jax_randcol(k0, k1, (uint32_t)i, NS1);
  int nid = batch[i / S2N];
  s1[i] = adj[(size_t)nid * MAX_DEG + col];
}

// ---------------------------------------------------------------------------
// K2: out_h1[r] = relu([ feat[s1[r]] @ Ws0 | mean_t feat[s2[r,t]] @ Wn0 ])
#define R2 8
__global__ __launch_bounds__(256) void k_h1(const float* __restrict__ feat,
                                            const int* __restrict__ adj,
                                            const int* __restrict__ s1,
                                            const float* __restrict__ Ws,
                                            const float* __restrict__ Wn,
                                            float* __restrict__ h1out) {
  __shared__ int   nbr[R2 * S1N];
  __shared__ int   selfid[R2];
  __shared__ float sh[2][R2][F_DIM];   // [0]=self vec, [1]=neigh mean
  const int tid = threadIdx.x;
  const int r0 = blockIdx.x * R2;

  if (tid < R2 * S1N) {
    int rr = tid / S1N, t = tid % S1N;
    int r = r0 + rr;
    uint32_t k0, k1;
    jax_subkey(1, k0, k1);
    uint32_t col = jax_randcol(k0, k1, (uint32_t)(r * S1N + t), NS2);
    int sn = s1[r];
    nbr[tid] = adj[(size_t)sn * MAX_DEG + col];
    if (t == 0) selfid[rr] = sn;
  }
  __syncthreads();

  for (int rr = 0; rr < R2; ++rr) {
    float acc = 0.f;
#pragma unroll
    for (int t = 0; t < S1N; ++t)
      acc += feat[(size_t)nbr[rr * S1N + t] * F_DIM + tid];
    sh[1][rr][tid] = acc / (float)S1N;
    sh[0][rr][tid] = feat[(size_t)selfid[rr] * F_DIM + tid];
  }
  __syncthreads();

  const int j = tid & (H_DIM - 1);
  const int half = tid >> 7;                 // 0 -> self@Ws, 1 -> mean@Wn
  const float* __restrict__ W = half ? Wn : Ws;
  float acc[R2];
#pragma unroll
  for (int rr = 0; rr < R2; ++rr) acc[rr] = 0.f;
#pragma unroll 4
  for (int k = 0; k < F_DIM; ++k) {
    float w = W[k * H_DIM + j];
#pragma unroll
    for (int rr = 0; rr < R2; ++rr) acc[rr] += sh[half][rr][k] * w;
  }
#pragma unroll
  for (int rr = 0; rr < R2; ++rr)
    h1out[(size_t)(r0 + rr) * (2 * H_DIM) + half * H_DIM + j] = fmaxf(acc[rr], 0.f);
}

// ---------------------------------------------------------------------------
// K3: out_h0[b] = relu([ feat[batch[b]] @ Ws0 | mean_j feat[s1[b*10+j]] @ Wn0 ])
#define R3 2
__global__ __launch_bounds__(256) void k_h0(const float* __restrict__ feat,
                                            const int* __restrict__ batch,
                                            const int* __restrict__ s1,
                                            const float* __restrict__ Ws,
                                            const float* __restrict__ Wn,
                                            float* __restrict__ h0out) {
  __shared__ float sh[2][R3][F_DIM];
  const int tid = threadIdx.x;
  const int r0 = blockIdx.x * R3;

  for (int rr = 0; rr < R3; ++rr) {
    int b = r0 + rr;
    float acc = 0.f;
#pragma unroll
    for (int t = 0; t < S2N; ++t)
      acc += feat[(size_t)s1[b * S2N + t] * F_DIM + tid];
    sh[1][rr][tid] = acc / (float)S2N;
    sh[0][rr][tid] = feat[(size_t)batch[b] * F_DIM + tid];
  }
  __syncthreads();

  const int j = tid & (H_DIM - 1);
  const int half = tid >> 7;
  const float* __restrict__ W = half ? Wn : Ws;
  float acc[R3];
#pragma unroll
  for (int rr = 0; rr < R3; ++rr) acc[rr] = 0.f;
#pragma unroll 4
  for (int k = 0; k < F_DIM; ++k) {
    float w = W[k * H_DIM + j];
#pragma unroll
    for (int rr = 0; rr < R3; ++rr) acc[rr] += sh[half][rr][k] * w;
  }
#pragma unroll
  for (int rr = 0; rr < R3; ++rr)
    h0out[(size_t)(r0 + rr) * (2 * H_DIM) + half * H_DIM + j] = fmaxf(acc[rr], 0.f);
}

// ---------------------------------------------------------------------------
// K4: out[b] = l2norm([ h0out[b] @ Ws1 | mean_j h1out[b*10+j] @ Wn1 ])
__global__ __launch_bounds__(256) void k_out(const float* __restrict__ h0out,
                                             const float* __restrict__ h1out,
                                             const float* __restrict__ Ws,
                                             const float* __restrict__ Wn,
                                             float* __restrict__ out) {
  __shared__ float sh[2][R3][F_DIM];
  __shared__ float shout[R3][F_DIM];
  __shared__ float red[R3][4];
  __shared__ float shinv[R3];
  const int tid = threadIdx.x;
  const int r0 = blockIdx.x * R3;

  for (int rr = 0; rr < R3; ++rr) {
    int b = r0 + rr;
    float acc = 0.f;
#pragma unroll
    for (int t = 0; t < S2N; ++t)
      acc += h1out[(size_t)(b * S2N + t) * F_DIM + tid];
    sh[1][rr][tid] = acc / (float)S2N;
    sh[0][rr][tid] = h0out[(size_t)b * F_DIM + tid];
  }
  __syncthreads();

  const int j = tid & (H_DIM - 1);
  const int half = tid >> 7;
  const float* __restrict__ W = half ? Wn : Ws;
  float acc[R3];
#pragma unroll
  for (int rr = 0; rr < R3; ++rr) acc[rr] = 0.f;
#pragma unroll 4
  for (int k = 0; k < F_DIM; ++k) {
    float w = W[k * H_DIM + j];
#pragma unroll
    for (int rr = 0; rr < R3; ++rr) acc[rr] += sh[half][rr][k] * w;
  }
#pragma unroll
  for (int rr = 0; rr < R3; ++rr) shout[rr][tid] = acc[rr];
  __syncthreads();

#pragma unroll
  for (int rr = 0; rr < R3; ++rr) {
    float v = shout[rr][tid];
    float s = v * v;
#pragma unroll
    for (int off = 32; off > 0; off >>= 1) s += __shfl_xor(s, off);
    if ((tid & 63) == 0) red[rr][tid >> 6] = s;
  }
  __syncthreads();
  if (tid < R3) {
    float s = red[tid][0] + red[tid][1] + red[tid][2] + red[tid][3];
    shinv[tid] = 1.f / fmaxf(sqrtf(s), 1e-12f);
  }
  __syncthreads();
#pragma unroll
  for (int rr = 0; rr < R3; ++rr)
    out[(size_t)(r0 + rr) * F_DIM + tid] = shout[rr][tid] * shinv[rr];
}

// ---------------------------------------------------------------------------
extern "C" void kernel_launch(void* const* d_in, const int* in_sizes, int n_in,
                              void* d_out, int out_size, void* d_ws, size_t ws_size,
                              hipStream_t stream) {
  const float* feat  = (const float*)d_in[0];
  const int*   adj   = (const int*)d_in[1];
  const int*   batch = (const int*)d_in[2];
  const float* Ws0   = (const float*)d_in[3];
  const float* Wn0   = (const float*)d_in[4];
  const float* Ws1   = (const float*)d_in[5];
  const float* Wn1   = (const float*)d_in[6];
  float* out = (float*)d_out;

  char* ws = (char*)d_ws;
  int*   s1    = (int*)ws;                                       // 5120 * 4B
  float* h1out = (float*)(ws + 20480);                           // 5120*256*4B
  float* h0out = (float*)(ws + 20480 + (size_t)NS1 * F_DIM * 4); // 512*256*4B

  k_sample1<<<(NS1 + 255) / 256, 256, 0, stream>>>(adj, batch, s1);
  k_h1<<<NS1 / R2, 256, 0, stream>>>(feat, adj, s1, Ws0, Wn0, h1out);
  k_h0<<<BATCH / R3, 256, 0, stream>>>(feat, batch, s1, Ws0, Wn0, h0out);
  k_out<<<BATCH / R3, 256, 0, stream>>>(h0out, h1out, Ws1, Wn1, out);
}

// Round 6
// 66.048 us; speedup vs baseline: 1.1677x; 1.1677x over previous
//
#include <hip/hip_runtime.h>
#include <stdint.h>

// ---------------------------------------------------------------------------
// GraphSAGE SampleAndAggregate — RNG VERIFIED (round 5, variant 5):
//   modern JAX: partitionable threefry, foldlike split, and randint's
//   INTERNAL k1,k2=split(key); col_i = (x0^x1)(tf(tf(key,(0,1)),(0,i))) & 127
// DO NOT change the RNG path.
// ---------------------------------------------------------------------------
#define N_NODES 100000
#define F_DIM   256
#define H_DIM   128
#define MAX_DEG 128
#define BATCH   512
#define S1N     25
#define S2N     10
#define NS1     (BATCH * S2N)   // 5120
#define NS2     (NS1 * S1N)     // 128000

__device__ __forceinline__ void tf2(uint32_t k0, uint32_t k1, uint32_t c0, uint32_t c1,
                                    uint32_t& o0, uint32_t& o1) {
  uint32_t ks0 = k0, ks1 = k1, ks2 = k0 ^ k1 ^ 0x1BD11BDAu;
  uint32_t x0 = c0 + ks0;
  uint32_t x1 = c1 + ks1;
#define TF_ROUND(r) { x0 += x1; x1 = (x1 << (r)) | (x1 >> (32 - (r))); x1 ^= x0; }
  TF_ROUND(13); TF_ROUND(15); TF_ROUND(26); TF_ROUND(6);
  x0 += ks1; x1 += ks2 + 1u;
  TF_ROUND(17); TF_ROUND(29); TF_ROUND(16); TF_ROUND(24);
  x0 += ks2; x1 += ks0 + 2u;
  TF_ROUND(13); TF_ROUND(15); TF_ROUND(26); TF_ROUND(6);
  x0 += ks0; x1 += ks1 + 3u;
  TF_ROUND(17); TF_ROUND(29); TF_ROUND(16); TF_ROUND(24);
  x0 += ks1; x1 += ks2 + 4u;
  TF_ROUND(13); TF_ROUND(15); TF_ROUND(26); TF_ROUND(6);
  x0 += ks2; x1 += ks0 + 5u;
#undef TF_ROUND
  o0 = x0; o1 = x1;
}

// col draw i of randint(subkey_idx, size, 0, 128) under verified semantics
__device__ __forceinline__ uint32_t jax_col(int subkey_idx, uint32_t i) {
  uint32_t k0, k1, kk0, kk1, o0, o1;
  tf2(0u, 42u, 0u, (uint32_t)subkey_idx, k0, k1);  // foldlike split of key(42)
  tf2(k0, k1, 0u, 1u, kk0, kk1);                   // randint internal k2
  tf2(kk0, kk1, 0u, i, o0, o1);                    // lower_bits draw i
  return (o0 ^ o1) & (MAX_DEG - 1);
}

// ---------------------------------------------------------------------------
// K1: s1[i] = adj[batch[i/10], col(subkey0, i)]   (grid 20, 256 thr)
__global__ __launch_bounds__(256) void k_sample1(const int* __restrict__ adj,
                                                 const int* __restrict__ batch,
                                                 int* __restrict__ s1) {
  int i = blockIdx.x * 256 + threadIdx.x;
  if (i >= NS1) return;
  uint32_t col = jax_col(0, (uint32_t)i);
  int nid = batch[i / S2N];
  s1[i] = adj[(size_t)nid * MAX_DEG + col];
}

// ---------------------------------------------------------------------------
// K2: gather/mean. One s1-row per block (grid 5120, 256 thr).
//     X[r][0:256] = feat[s1[r]];  X[r][256:512] = mean_t feat[adj[s1[r], col_t]]
__global__ __launch_bounds__(256) void k_gather(const float* __restrict__ feat,
                                                const int* __restrict__ adj,
                                                const int* __restrict__ s1,
                                                float* __restrict__ X) {
  __shared__ int nbr[S1N];
  const int tid = threadIdx.x;
  const int r = blockIdx.x;
  const int sid = s1[r];

  if (tid < S1N) {
    uint32_t col = jax_col(1, (uint32_t)(r * S1N + tid));
    nbr[tid] = adj[(size_t)sid * MAX_DEG + col];
  }
  __syncthreads();

  float acc = 0.f;
#pragma unroll
  for (int t = 0; t < S1N; ++t)
    acc += feat[(size_t)nbr[t] * F_DIM + tid];

  X[(size_t)r * 512 + tid]       = feat[(size_t)sid * F_DIM + tid];
  X[(size_t)r * 512 + 256 + tid] = acc / (float)S1N;
}

// ---------------------------------------------------------------------------
// K3: h1out = relu([X_self @ Ws | X_mean @ Wn]).  grid 640, 8 rows/block.
//     X staged transposed in LDS as xl[rowgroup][k][row%4] -> per-k the wave
//     does 2 uniform-address ds_read_b128 (broadcast) + 8 FMA.
#define RMM 8
__global__ __launch_bounds__(256) void k_mm1(const float* __restrict__ X,
                                             const float* __restrict__ Ws,
                                             const float* __restrict__ Wn,
                                             float* __restrict__ h1out) {
  __shared__ float xl[2][512][4];   // 16 KB
  const int tid = threadIdx.x;
  const int r0 = blockIdx.x * RMM;

  // stage 8 rows x 512 cols, float4 global reads (fully contiguous)
#pragma unroll
  for (int c = 0; c < 4; ++c) {
    int flat = (c * 256 + tid) * 4;               // 0..4095, mult of 4
    float4 v = *reinterpret_cast<const float4*>(&X[(size_t)r0 * 512 + flat]);
    int rr = flat >> 9, k = flat & 511;
    int g = rr >> 2, rl = rr & 3;
    xl[g][k + 0][rl] = v.x; xl[g][k + 1][rl] = v.y;
    xl[g][k + 2][rl] = v.z; xl[g][k + 3][rl] = v.w;
  }
  __syncthreads();

  const int j = tid & (H_DIM - 1);
  const int h = tid >> 7;                          // 0: self@Ws, 1: mean@Wn
  const float* __restrict__ W = h ? Wn : Ws;
  float acc[RMM];
#pragma unroll
  for (int rr = 0; rr < RMM; ++rr) acc[rr] = 0.f;

#pragma unroll 4
  for (int k = 0; k < F_DIM; ++k) {
    float w = W[k * H_DIM + j];
    int kk = (h << 8) + k;                         // X column for this half
    float4 xa = *reinterpret_cast<const float4*>(&xl[0][kk][0]);
    float4 xb = *reinterpret_cast<const float4*>(&xl[1][kk][0]);
    acc[0] += xa.x * w; acc[1] += xa.y * w; acc[2] += xa.z * w; acc[3] += xa.w * w;
    acc[4] += xb.x * w; acc[5] += xb.y * w; acc[6] += xb.z * w; acc[7] += xb.w * w;
  }
#pragma unroll
  for (int rr = 0; rr < RMM; ++rr)
    h1out[(size_t)(r0 + rr) * 256 + (h << 7) + j] = fmaxf(acc[rr], 0.f);
}

// ---------------------------------------------------------------------------
// K4 (fused h0 + out): per batch row b (grid 512, 256 thr):
//   h0 = relu([feat[batch[b]] @ Ws0 | mean_t X[b*10+t][0:256] @ Wn0])
//   o  = [h0 @ Ws1 | mean_t h1out[b*10+t] @ Wn1];  out = o / max(||o||, 1e-12)
__global__ __launch_bounds__(256) void k_tail(const float* __restrict__ feat,
                                              const int* __restrict__ batch,
                                              const float* __restrict__ X,
                                              const float* __restrict__ h1out,
                                              const float* __restrict__ Ws0,
                                              const float* __restrict__ Wn0,
                                              const float* __restrict__ Ws1,
                                              const float* __restrict__ Wn1,
                                              float* __restrict__ out) {
  __shared__ float sA[2][F_DIM];
  __shared__ float sB[2][F_DIM];
  __shared__ float red[4];
  const int tid = threadIdx.x;
  const int b = blockIdx.x;
  const int j = tid & (H_DIM - 1);
  const int h = tid >> 7;

  // layer-0 inputs: self feat + neighbor-mean (from X's self half, coalesced)
  {
    float m = 0.f;
#pragma unroll
    for (int t = 0; t < S2N; ++t)
      m += X[(size_t)(b * S2N + t) * 512 + tid];
    sA[1][tid] = m / (float)S2N;
    sA[0][tid] = feat[(size_t)batch[b] * F_DIM + tid];
  }
  __syncthreads();

  // h0 column tid
  const float* __restrict__ W0 = h ? Wn0 : Ws0;
  float a0 = 0.f;
#pragma unroll 4
  for (int k4 = 0; k4 < F_DIM / 4; ++k4) {
    float4 s4 = *reinterpret_cast<const float4*>(&sA[h][k4 * 4]);
    a0 += s4.x * W0[(k4 * 4 + 0) * H_DIM + j];
    a0 += s4.y * W0[(k4 * 4 + 1) * H_DIM + j];
    a0 += s4.z * W0[(k4 * 4 + 2) * H_DIM + j];
    a0 += s4.w * W0[(k4 * 4 + 3) * H_DIM + j];
  }
  a0 = fmaxf(a0, 0.f);

  // layer-1 inputs
  sB[0][tid] = a0;
  {
    float m = 0.f;
#pragma unroll
    for (int t = 0; t < S2N; ++t)
      m += h1out[(size_t)(b * S2N + t) * 256 + tid];
    sB[1][tid] = m / (float)S2N;
  }
  __syncthreads();

  const float* __restrict__ W1 = h ? Wn1 : Ws1;
  float a1 = 0.f;
#pragma unroll 4
  for (int k4 = 0; k4 < F_DIM / 4; ++k4) {
    float4 s4 = *reinterpret_cast<const float4*>(&sB[h][k4 * 4]);
    a1 += s4.x * W1[(k4 * 4 + 0) * H_DIM + j];
    a1 += s4.y * W1[(k4 * 4 + 1) * H_DIM + j];
    a1 += s4.z * W1[(k4 * 4 + 2) * H_DIM + j];
    a1 += s4.w * W1[(k4 * 4 + 3) * H_DIM + j];
  }

  // row L2-norm across the 256 output columns
  float s = a1 * a1;
#pragma unroll
  for (int off = 32; off > 0; off >>= 1) s += __shfl_xor(s, off);
  if ((tid & 63) == 0) red[tid >> 6] = s;
  __syncthreads();
  float tot = red[0] + red[1] + red[2] + red[3];
  float inv = 1.f / fmaxf(sqrtf(tot), 1e-12f);
  out[(size_t)b * 256 + tid] = a1 * inv;
}

// ---------------------------------------------------------------------------
extern "C" void kernel_launch(void* const* d_in, const int* in_sizes, int n_in,
                              void* d_out, int out_size, void* d_ws, size_t ws_size,
                              hipStream_t stream) {
  const float* feat  = (const float*)d_in[0];
  const int*   adj   = (const int*)d_in[1];
  const int*   batch = (const int*)d_in[2];
  const float* Ws0   = (const float*)d_in[3];
  const float* Wn0   = (const float*)d_in[4];
  const float* Ws1   = (const float*)d_in[5];
  const float* Wn1   = (const float*)d_in[6];
  float* out = (float*)d_out;

  char* ws = (char*)d_ws;
  int*   s1    = (int*)ws;                        // 20 KB
  float* X     = (float*)(ws + (1u << 20));       // 5120*512*4 = 10.5 MB
  float* h1out = (float*)(ws + (16u << 20));      // 5120*256*4 = 5.25 MB

  k_sample1<<<(NS1 + 255) / 256, 256, 0, stream>>>(adj, batch, s1);
  k_gather <<<NS1, 256, 0, stream>>>(feat, adj, s1, X);
  k_mm1    <<<NS1 / RMM, 256, 0, stream>>>(X, Ws0, Wn0, h1out);
  k_tail   <<<BATCH, 256, 0, stream>>>(feat, batch, X, h1out, Ws0, Wn0, Ws1, Wn1, out);
}

// Round 7
// 62.821 us; speedup vs baseline: 1.2276x; 1.0514x over previous
//
#include <hip/hip_runtime.h>
#include <stdint.h>

// ---------------------------------------------------------------------------
// GraphSAGE SampleAndAggregate — RNG VERIFIED (round 5, variant 5):
//   modern JAX: partitionable threefry, foldlike split, and randint's
//   INTERNAL k1,k2=split(key); col_i = (x0^x1)(tf(tf(key,(0,1)),(0,i))) & 127
// DO NOT change the RNG path.
// ---------------------------------------------------------------------------
#define N_NODES 100000
#define F_DIM   256
#define H_DIM   128
#define MAX_DEG 128
#define BATCH   512
#define S1N     25
#define S2N     10
#define NS1     (BATCH * S2N)   // 5120
#define NS2     (NS1 * S1N)     // 128000

__device__ __forceinline__ void tf2(uint32_t k0, uint32_t k1, uint32_t c0, uint32_t c1,
                                    uint32_t& o0, uint32_t& o1) {
  uint32_t ks0 = k0, ks1 = k1, ks2 = k0 ^ k1 ^ 0x1BD11BDAu;
  uint32_t x0 = c0 + ks0;
  uint32_t x1 = c1 + ks1;
#define TF_ROUND(r) { x0 += x1; x1 = (x1 << (r)) | (x1 >> (32 - (r))); x1 ^= x0; }
  TF_ROUND(13); TF_ROUND(15); TF_ROUND(26); TF_ROUND(6);
  x0 += ks1; x1 += ks2 + 1u;
  TF_ROUND(17); TF_ROUND(29); TF_ROUND(16); TF_ROUND(24);
  x0 += ks2; x1 += ks0 + 2u;
  TF_ROUND(13); TF_ROUND(15); TF_ROUND(26); TF_ROUND(6);
  x0 += ks0; x1 += ks1 + 3u;
  TF_ROUND(17); TF_ROUND(29); TF_ROUND(16); TF_ROUND(24);
  x0 += ks1; x1 += ks2 + 4u;
  TF_ROUND(13); TF_ROUND(15); TF_ROUND(26); TF_ROUND(6);
  x0 += ks2; x1 += ks0 + 5u;
#undef TF_ROUND
  o0 = x0; o1 = x1;
}

// col draw i of randint(subkey_idx, ..., 0, 128) under verified semantics
__device__ __forceinline__ uint32_t jax_col(int subkey_idx, uint32_t i) {
  uint32_t k0, k1, kk0, kk1, o0, o1;
  tf2(0u, 42u, 0u, (uint32_t)subkey_idx, k0, k1);  // foldlike split of key(42)
  tf2(k0, k1, 0u, 1u, kk0, kk1);                   // randint internal k2
  tf2(kk0, kk1, 0u, i, o0, o1);                    // lower_bits draw i
  return (o0 ^ o1) & (MAX_DEG - 1);
}

// ---------------------------------------------------------------------------
// K1 (fused sample+gather): one s1-row per block (grid 5120, 256 thr).
//   s1 = adj[batch[r/10], col0(r)]  (computed inline, redundantly per lane)
//   X[r][0:256]   = feat[s1]
//   X[r][256:512] = mean_t feat[adj[s1, col1(r*25+t)]]
// Vectorized: each wave reads whole 1-KB rows as float4/lane; 26 sources
// split across 4 waves; partial sums combined via LDS.
__global__ __launch_bounds__(256) void k_gather(const float* __restrict__ feat,
                                                const int* __restrict__ adj,
                                                const int* __restrict__ batch,
                                                float* __restrict__ X) {
  __shared__ int   nbr[26];        // [25] = self (s1)
  __shared__ float ps[4][256];     // per-wave partial sums
  const int tid = threadIdx.x;
  const int r = blockIdx.x;

  if (tid < 26) {
    // all 26 lanes compute s1 redundantly (identical chain, ~3 tf2)
    uint32_t c0 = jax_col(0, (uint32_t)r);
    int s1 = adj[(size_t)batch[r / S2N] * MAX_DEG + c0];
    if (tid < 25) {
      uint32_t col = jax_col(1, (uint32_t)(r * S1N + tid));
      nbr[tid] = adj[(size_t)s1 * MAX_DEG + col];
    } else {
      nbr[25] = s1;
    }
  }
  __syncthreads();

  const int w = tid >> 6, lane = tid & 63;
  float4 acc = make_float4(0.f, 0.f, 0.f, 0.f);
  for (int t = w; t < 26; t += 4) {
    const float4 v =
        *reinterpret_cast<const float4*>(&feat[(size_t)nbr[t] * F_DIM + lane * 4]);
    if (t == 25) {
      // self row: store straight through, excluded from the mean
      *reinterpret_cast<float4*>(&X[(size_t)r * 512 + lane * 4]) = v;
    } else {
      acc.x += v.x; acc.y += v.y; acc.z += v.z; acc.w += v.w;
    }
  }
  *reinterpret_cast<float4*>(&ps[w][lane * 4]) = acc;
  __syncthreads();

  float m = ps[0][tid] + ps[1][tid] + ps[2][tid] + ps[3][tid];
  X[(size_t)r * 512 + 256 + tid] = m / (float)S1N;
}

// ---------------------------------------------------------------------------
// K2: h1out = relu([X_self @ Ws | X_mean @ Wn]).  grid 640, 8 rows/block.
//     (unchanged from round 6 — verified)
#define RMM 8
__global__ __launch_bounds__(256) void k_mm1(const float* __restrict__ X,
                                             const float* __restrict__ Ws,
                                             const float* __restrict__ Wn,
                                             float* __restrict__ h1out) {
  __shared__ float xl[2][512][4];   // 16 KB
  const int tid = threadIdx.x;
  const int r0 = blockIdx.x * RMM;

#pragma unroll
  for (int c = 0; c < 4; ++c) {
    int flat = (c * 256 + tid) * 4;               // 0..4095, mult of 4
    float4 v = *reinterpret_cast<const float4*>(&X[(size_t)r0 * 512 + flat]);
    int rr = flat >> 9, k = flat & 511;
    int g = rr >> 2, rl = rr & 3;
    xl[g][k + 0][rl] = v.x; xl[g][k + 1][rl] = v.y;
    xl[g][k + 2][rl] = v.z; xl[g][k + 3][rl] = v.w;
  }
  __syncthreads();

  const int j = tid & (H_DIM - 1);
  const int h = tid >> 7;                          // 0: self@Ws, 1: mean@Wn
  const float* __restrict__ W = h ? Wn : Ws;
  float acc[RMM];
#pragma unroll
  for (int rr = 0; rr < RMM; ++rr) acc[rr] = 0.f;

#pragma unroll 4
  for (int k = 0; k < F_DIM; ++k) {
    float w = W[k * H_DIM + j];
    int kk = (h << 8) + k;                         // X column for this half
    float4 xa = *reinterpret_cast<const float4*>(&xl[0][kk][0]);
    float4 xb = *reinterpret_cast<const float4*>(&xl[1][kk][0]);
    acc[0] += xa.x * w; acc[1] += xa.y * w; acc[2] += xa.z * w; acc[3] += xa.w * w;
    acc[4] += xb.x * w; acc[5] += xb.y * w; acc[6] += xb.z * w; acc[7] += xb.w * w;
  }
#pragma unroll
  for (int rr = 0; rr < RMM; ++rr)
    h1out[(size_t)(r0 + rr) * 256 + (h << 7) + j] = fmaxf(acc[rr], 0.f);
}

// ---------------------------------------------------------------------------
// K3 (fused h0 + out): per batch row b (grid 512, 256 thr). Unchanged.
__global__ __launch_bounds__(256) void k_tail(const float* __restrict__ feat,
                                              const int* __restrict__ batch,
                                              const float* __restrict__ X,
                                              const float* __restrict__ h1out,
                                              const float* __restrict__ Ws0,
                                              const float* __restrict__ Wn0,
                                              const float* __restrict__ Ws1,
                                              const float* __restrict__ Wn1,
                                              float* __restrict__ out) {
  __shared__ float sA[2][F_DIM];
  __shared__ float sB[2][F_DIM];
  __shared__ float red[4];
  const int tid = threadIdx.x;
  const int b = blockIdx.x;
  const int j = tid & (H_DIM - 1);
  const int h = tid >> 7;

  {
    float m = 0.f;
#pragma unroll
    for (int t = 0; t < S2N; ++t)
      m += X[(size_t)(b * S2N + t) * 512 + tid];
    sA[1][tid] = m / (float)S2N;
    sA[0][tid] = feat[(size_t)batch[b] * F_DIM + tid];
  }
  __syncthreads();

  const float* __restrict__ W0 = h ? Wn0 : Ws0;
  float a0 = 0.f;
#pragma unroll 4
  for (int k4 = 0; k4 < F_DIM / 4; ++k4) {
    float4 s4 = *reinterpret_cast<const float4*>(&sA[h][k4 * 4]);
    a0 += s4.x * W0[(k4 * 4 + 0) * H_DIM + j];
    a0 += s4.y * W0[(k4 * 4 + 1) * H_DIM + j];
    a0 += s4.z * W0[(k4 * 4 + 2) * H_DIM + j];
    a0 += s4.w * W0[(k4 * 4 + 3) * H_DIM + j];
  }
  a0 = fmaxf(a0, 0.f);

  sB[0][tid] = a0;
  {
    float m = 0.f;
#pragma unroll
    for (int t = 0; t < S2N; ++t)
      m += h1out[(size_t)(b * S2N + t) * 256 + tid];
    sB[1][tid] = m / (float)S2N;
  }
  __syncthreads();

  const float* __restrict__ W1 = h ? Wn1 : Ws1;
  float a1 = 0.f;
#pragma unroll 4
  for (int k4 = 0; k4 < F_DIM / 4; ++k4) {
    float4 s4 = *reinterpret_cast<const float4*>(&sB[h][k4 * 4]);
    a1 += s4.x * W1[(k4 * 4 + 0) * H_DIM + j];
    a1 += s4.y * W1[(k4 * 4 + 1) * H_DIM + j];
    a1 += s4.z * W1[(k4 * 4 + 2) * H_DIM + j];
    a1 += s4.w * W1[(k4 * 4 + 3) * H_DIM + j];
  }

  float s = a1 * a1;
#pragma unroll
  for (int off = 32; off > 0; off >>= 1) s += __shfl_xor(s, off);
  if ((tid & 63) == 0) red[tid >> 6] = s;
  __syncthreads();
  float tot = red[0] + red[1] + red[2] + red[3];
  float inv = 1.f / fmaxf(sqrtf(tot), 1e-12f);
  out[(size_t)b * 256 + tid] = a1 * inv;
}

// ---------------------------------------------------------------------------
extern "C" void kernel_launch(void* const* d_in, const int* in_sizes, int n_in,
                              void* d_out, int out_size, void* d_ws, size_t ws_size,
                              hipStream_t stream) {
  const float* feat  = (const float*)d_in[0];
  const int*   adj   = (const int*)d_in[1];
  const int*   batch = (const int*)d_in[2];
  const float* Ws0   = (const float*)d_in[3];
  const float* Wn0   = (const float*)d_in[4];
  const float* Ws1   = (const float*)d_in[5];
  const float* Wn1   = (const float*)d_in[6];
  float* out = (float*)d_out;

  char* ws = (char*)d_ws;
  float* X     = (float*)(ws);                    // 5120*512*4 = 10.5 MB
  float* h1out = (float*)(ws + (16u << 20));      // 5120*256*4 = 5.25 MB

  k_gather<<<NS1, 256, 0, stream>>>(feat, adj, batch, X);
  k_mm1   <<<NS1 / RMM, 256, 0, stream>>>(X, Ws0, Wn0, h1out);
  k_tail  <<<BATCH, 256, 0, stream>>>(feat, batch, X, h1out, Ws0, Wn0, Ws1, Wn1, out);
}

// Round 8
// 57.514 us; speedup vs baseline: 1.3409x; 1.0923x over previous
//
#include <hip/hip_runtime.h>
#include <stdint.h>

// ---------------------------------------------------------------------------
// GraphSAGE SampleAndAggregate — RNG VERIFIED (round 5, variant 5):
//   modern JAX: partitionable threefry, foldlike split, and randint's
//   INTERNAL k1,k2=split(key); col_i = (x0^x1)(tf(tf(key,(0,1)),(0,i))) & 127
// DO NOT change the RNG path.
// ---------------------------------------------------------------------------
#define N_NODES 100000
#define F_DIM   256
#define H_DIM   128
#define MAX_DEG 128
#define BATCH   512
#define S1N     25
#define S2N     10
#define NS1     (BATCH * S2N)   // 5120
#define NS2     (NS1 * S1N)     // 128000

__device__ __forceinline__ void tf2(uint32_t k0, uint32_t k1, uint32_t c0, uint32_t c1,
                                    uint32_t& o0, uint32_t& o1) {
  uint32_t ks0 = k0, ks1 = k1, ks2 = k0 ^ k1 ^ 0x1BD11BDAu;
  uint32_t x0 = c0 + ks0;
  uint32_t x1 = c1 + ks1;
#define TF_ROUND(r) { x0 += x1; x1 = (x1 << (r)) | (x1 >> (32 - (r))); x1 ^= x0; }
  TF_ROUND(13); TF_ROUND(15); TF_ROUND(26); TF_ROUND(6);
  x0 += ks1; x1 += ks2 + 1u;
  TF_ROUND(17); TF_ROUND(29); TF_ROUND(16); TF_ROUND(24);
  x0 += ks2; x1 += ks0 + 2u;
  TF_ROUND(13); TF_ROUND(15); TF_ROUND(26); TF_ROUND(6);
  x0 += ks0; x1 += ks1 + 3u;
  TF_ROUND(17); TF_ROUND(29); TF_ROUND(16); TF_ROUND(24);
  x0 += ks1; x1 += ks2 + 4u;
  TF_ROUND(13); TF_ROUND(15); TF_ROUND(26); TF_ROUND(6);
  x0 += ks2; x1 += ks0 + 5u;
#undef TF_ROUND
  o0 = x0; o1 = x1;
}

// col draw i of randint(subkey_idx, ..., 0, 128) under verified semantics
__device__ __forceinline__ uint32_t jax_col(int subkey_idx, uint32_t i) {
  uint32_t k0, k1, kk0, kk1, o0, o1;
  tf2(0u, 42u, 0u, (uint32_t)subkey_idx, k0, k1);  // foldlike split of key(42)
  tf2(k0, k1, 0u, 1u, kk0, kk1);                   // randint internal k2
  tf2(kk0, kk1, 0u, i, o0, o1);                    // lower_bits draw i
  return (o0 ^ o1) & (MAX_DEG - 1);
}

// ---------------------------------------------------------------------------
// K1 (fused sample + gather + layer-0 matmul for the 5120 h1 rows).
// Grid 640, block 256. Each block owns 8 s1-rows:
//   per row r: s1 = adj[batch[r/10], col0(r)]
//              self = feat[s1]               -> Xself[r], xl[.][k<256][.]
//              mean = mean_t feat[adj[s1, col1(r*25+t)]] -> xl[.][k>=256][.]
//   then h1out[r] = relu([self @ Ws | mean @ Wn])   (identical math to r6 mm)
#define RMM 8
__global__ __launch_bounds__(256) void k_gmm(const float* __restrict__ feat,
                                             const int* __restrict__ adj,
                                             const int* __restrict__ batch,
                                             const float* __restrict__ Ws,
                                             const float* __restrict__ Wn,
                                             float* __restrict__ Xself,
                                             float* __restrict__ h1out) {
  __shared__ int   nbr[RMM][26];    // [.][25] = self (s1)
  __shared__ float xl[2][512][4];   // 16 KB, transposed X tile
  const int tid = threadIdx.x;
  const int r0 = blockIdx.x * RMM;

  if (tid < RMM * 26) {
    int rr = tid / 26, t = tid % 26;
    int r = r0 + rr;
    uint32_t c0 = jax_col(0, (uint32_t)r);
    int s1 = adj[(size_t)batch[r / S2N] * MAX_DEG + c0];
    if (t < 25) {
      uint32_t col = jax_col(1, (uint32_t)(r * S1N + t));
      nbr[rr][t] = adj[(size_t)s1 * MAX_DEG + col];
    } else {
      nbr[rr][25] = s1;
    }
  }
  __syncthreads();

  // ---- gather phase: 8 groups of 32 lanes, one row each; 8 floats/lane ----
  const int g = tid >> 5, lane = tid & 31;
  const int k0 = lane * 8;
  float4 a0 = make_float4(0.f, 0.f, 0.f, 0.f);
  float4 a1 = make_float4(0.f, 0.f, 0.f, 0.f);
#pragma unroll 5
  for (int t = 0; t < 25; ++t) {
    const float* p = &feat[(size_t)nbr[g][t] * F_DIM + k0];
    float4 v0 = *reinterpret_cast<const float4*>(p);
    float4 v1 = *reinterpret_cast<const float4*>(p + 4);
    a0.x += v0.x; a0.y += v0.y; a0.z += v0.z; a0.w += v0.w;
    a1.x += v1.x; a1.y += v1.y; a1.z += v1.z; a1.w += v1.w;
  }
  const float* ps = &feat[(size_t)nbr[g][25] * F_DIM + k0];
  float4 s0 = *reinterpret_cast<const float4*>(ps);
  float4 s1v = *reinterpret_cast<const float4*>(ps + 4);

  // self half also goes to global for k_tail's h0-neighbor-mean
  *reinterpret_cast<float4*>(&Xself[(size_t)(r0 + g) * 256 + k0])     = s0;
  *reinterpret_cast<float4*>(&Xself[(size_t)(r0 + g) * 256 + k0 + 4]) = s1v;

  // transposed LDS store (one-time; 32-way bank conflict here is negligible)
  {
    const int G = g >> 2, rl = g & 3;
    const float inv = 1.f / (float)S1N;
    xl[G][k0 + 0][rl] = s0.x;  xl[G][k0 + 1][rl] = s0.y;
    xl[G][k0 + 2][rl] = s0.z;  xl[G][k0 + 3][rl] = s0.w;
    xl[G][k0 + 4][rl] = s1v.x; xl[G][k0 + 5][rl] = s1v.y;
    xl[G][k0 + 6][rl] = s1v.z; xl[G][k0 + 7][rl] = s1v.w;
    xl[G][256 + k0 + 0][rl] = a0.x * inv; xl[G][256 + k0 + 1][rl] = a0.y * inv;
    xl[G][256 + k0 + 2][rl] = a0.z * inv; xl[G][256 + k0 + 3][rl] = a0.w * inv;
    xl[G][256 + k0 + 4][rl] = a1.x * inv; xl[G][256 + k0 + 5][rl] = a1.y * inv;
    xl[G][256 + k0 + 6][rl] = a1.z * inv; xl[G][256 + k0 + 7][rl] = a1.w * inv;
  }
  __syncthreads();

  // ---- mm phase (identical math to verified round-6 k_mm1) ----
  const int j = tid & (H_DIM - 1);
  const int h = tid >> 7;                          // 0: self@Ws, 1: mean@Wn
  const float* __restrict__ W = h ? Wn : Ws;
  float acc[RMM];
#pragma unroll
  for (int rr = 0; rr < RMM; ++rr) acc[rr] = 0.f;

#pragma unroll 4
  for (int k = 0; k < F_DIM; ++k) {
    float w = W[k * H_DIM + j];
    int kk = (h << 8) + k;
    float4 xa = *reinterpret_cast<const float4*>(&xl[0][kk][0]);
    float4 xb = *reinterpret_cast<const float4*>(&xl[1][kk][0]);
    acc[0] += xa.x * w; acc[1] += xa.y * w; acc[2] += xa.z * w; acc[3] += xa.w * w;
    acc[4] += xb.x * w; acc[5] += xb.y * w; acc[6] += xb.z * w; acc[7] += xb.w * w;
  }
#pragma unroll
  for (int rr = 0; rr < RMM; ++rr)
    h1out[(size_t)(r0 + rr) * 256 + (h << 7) + j] = fmaxf(acc[rr], 0.f);
}

// ---------------------------------------------------------------------------
// K2 (fused h0 + out): per batch row b (grid 512, 256 thr).
// Same as verified round-6 k_tail, with X self-half re-strided 512 -> 256.
__global__ __launch_bounds__(256) void k_tail(const float* __restrict__ feat,
                                              const int* __restrict__ batch,
                                              const float* __restrict__ Xself,
                                              const float* __restrict__ h1out,
                                              const float* __restrict__ Ws0,
                                              const float* __restrict__ Wn0,
                                              const float* __restrict__ Ws1,
                                              const float* __restrict__ Wn1,
                                              float* __restrict__ out) {
  __shared__ float sA[2][F_DIM];
  __shared__ float sB[2][F_DIM];
  __shared__ float red[4];
  const int tid = threadIdx.x;
  const int b = blockIdx.x;
  const int j = tid & (H_DIM - 1);
  const int h = tid >> 7;

  {
    float m = 0.f;
#pragma unroll
    for (int t = 0; t < S2N; ++t)
      m += Xself[(size_t)(b * S2N + t) * 256 + tid];
    sA[1][tid] = m / (float)S2N;
    sA[0][tid] = feat[(size_t)batch[b] * F_DIM + tid];
  }
  __syncthreads();

  const float* __restrict__ W0 = h ? Wn0 : Ws0;
  float a0 = 0.f;
#pragma unroll 4
  for (int k4 = 0; k4 < F_DIM / 4; ++k4) {
    float4 s4 = *reinterpret_cast<const float4*>(&sA[h][k4 * 4]);
    a0 += s4.x * W0[(k4 * 4 + 0) * H_DIM + j];
    a0 += s4.y * W0[(k4 * 4 + 1) * H_DIM + j];
    a0 += s4.z * W0[(k4 * 4 + 2) * H_DIM + j];
    a0 += s4.w * W0[(k4 * 4 + 3) * H_DIM + j];
  }
  a0 = fmaxf(a0, 0.f);

  sB[0][tid] = a0;
  {
    float m = 0.f;
#pragma unroll
    for (int t = 0; t < S2N; ++t)
      m += h1out[(size_t)(b * S2N + t) * 256 + tid];
    sB[1][tid] = m / (float)S2N;
  }
  __syncthreads();

  const float* __restrict__ W1 = h ? Wn1 : Ws1;
  float a1 = 0.f;
#pragma unroll 4
  for (int k4 = 0; k4 < F_DIM / 4; ++k4) {
    float4 s4 = *reinterpret_cast<const float4*>(&sB[h][k4 * 4]);
    a1 += s4.x * W1[(k4 * 4 + 0) * H_DIM + j];
    a1 += s4.y * W1[(k4 * 4 + 1) * H_DIM + j];
    a1 += s4.z * W1[(k4 * 4 + 2) * H_DIM + j];
    a1 += s4.w * W1[(k4 * 4 + 3) * H_DIM + j];
  }

  float s = a1 * a1;
#pragma unroll
  for (int off = 32; off > 0; off >>= 1) s += __shfl_xor(s, off);
  if ((tid & 63) == 0) red[tid >> 6] = s;
  __syncthreads();
  float tot = red[0] + red[1] + red[2] + red[3];
  float inv = 1.f / fmaxf(sqrtf(tot), 1e-12f);
  out[(size_t)b * 256 + tid] = a1 * inv;
}

// ---------------------------------------------------------------------------
extern "C" void kernel_launch(void* const* d_in, const int* in_sizes, int n_in,
                              void* d_out, int out_size, void* d_ws, size_t ws_size,
                              hipStream_t stream) {
  const float* feat  = (const float*)d_in[0];
  const int*   adj   = (const int*)d_in[1];
  const int*   batch = (const int*)d_in[2];
  const float* Ws0   = (const float*)d_in[3];
  const float* Wn0   = (const float*)d_in[4];
  const float* Ws1   = (const float*)d_in[5];
  const float* Wn1   = (const float*)d_in[6];
  float* out = (float*)d_out;

  char* ws = (char*)d_ws;
  float* Xself = (float*)(ws);                    // 5120*256*4 = 5.25 MB
  float* h1out = (float*)(ws + (8u << 20));       // 5120*256*4 = 5.25 MB

  k_gmm <<<NS1 / RMM, 256, 0, stream>>>(feat, adj, batch, Ws0, Wn0, Xself, h1out);
  k_tail<<<BATCH, 256, 0, stream>>>(feat, batch, Xself, h1out, Ws0, Wn0, Ws1, Wn1, out);
}

// Round 9
// 54.205 us; speedup vs baseline: 1.4228x; 1.0610x over previous
//
#include <hip/hip_runtime.h>
#include <stdint.h>

// ---------------------------------------------------------------------------
// GraphSAGE SampleAndAggregate — RNG VERIFIED (round 5, variant 5):
//   modern JAX: partitionable threefry, foldlike split, and randint's
//   INTERNAL k1,k2=split(key); col_i = (x0^x1)(tf(tf(key,(0,1)),(0,i))) & 127
// DO NOT change the RNG path.
// ---------------------------------------------------------------------------
#define N_NODES 100000
#define F_DIM   256
#define H_DIM   128
#define MAX_DEG 128
#define BATCH   512
#define S1N     25
#define S2N     10
#define NS1     (BATCH * S2N)   // 5120
#define NS2     (NS1 * S1N)     // 128000

__device__ __forceinline__ void tf2(uint32_t k0, uint32_t k1, uint32_t c0, uint32_t c1,
                                    uint32_t& o0, uint32_t& o1) {
  uint32_t ks0 = k0, ks1 = k1, ks2 = k0 ^ k1 ^ 0x1BD11BDAu;
  uint32_t x0 = c0 + ks0;
  uint32_t x1 = c1 + ks1;
#define TF_ROUND(r) { x0 += x1; x1 = (x1 << (r)) | (x1 >> (32 - (r))); x1 ^= x0; }
  TF_ROUND(13); TF_ROUND(15); TF_ROUND(26); TF_ROUND(6);
  x0 += ks1; x1 += ks2 + 1u;
  TF_ROUND(17); TF_ROUND(29); TF_ROUND(16); TF_ROUND(24);
  x0 += ks2; x1 += ks0 + 2u;
  TF_ROUND(13); TF_ROUND(15); TF_ROUND(26); TF_ROUND(6);
  x0 += ks0; x1 += ks1 + 3u;
  TF_ROUND(17); TF_ROUND(29); TF_ROUND(16); TF_ROUND(24);
  x0 += ks1; x1 += ks2 + 4u;
  TF_ROUND(13); TF_ROUND(15); TF_ROUND(26); TF_ROUND(6);
  x0 += ks2; x1 += ks0 + 5u;
#undef TF_ROUND
  o0 = x0; o1 = x1;
}

// col draw i of randint(subkey_idx, ..., 0, 128) under verified semantics
__device__ __forceinline__ uint32_t jax_col(int subkey_idx, uint32_t i) {
  uint32_t k0, k1, kk0, kk1, o0, o1;
  tf2(0u, 42u, 0u, (uint32_t)subkey_idx, k0, k1);  // foldlike split of key(42)
  tf2(k0, k1, 0u, 1u, kk0, kk1);                   // randint internal k2
  tf2(kk0, kk1, 0u, i, o0, o1);                    // lower_bits draw i
  return (o0 ^ o1) & (MAX_DEG - 1);
}

// ---------------------------------------------------------------------------
// K1 (fused sample + gather + layer-0 matmul for the 5120 h1 rows).
// Grid 640, block 512 (8 waves -> ~20 waves/CU at 2.5 blocks/CU).
// Each block owns 8 s1-rows:
//   gather: 16 groups x 32 lanes; group g = (row rr = g>>1, feature-half g&1)
//   mm:     thread (q=tid>>8, h, j) computes rows q*4..q*4+3, col h*128+j
#define RMM 8
__global__ __launch_bounds__(512) void k_gmm(const float* __restrict__ feat,
                                             const int* __restrict__ adj,
                                             const int* __restrict__ batch,
                                             const float* __restrict__ Ws,
                                             const float* __restrict__ Wn,
                                             float* __restrict__ Xself,
                                             float* __restrict__ h1out) {
  __shared__ int   nbr[RMM][26];    // [.][25] = self (s1)
  __shared__ float xl[2][512][4];   // 16 KB, transposed X tile
  const int tid = threadIdx.x;
  const int r0 = blockIdx.x * RMM;

  if (tid < RMM * 26) {
    int rr = tid / 26, t = tid % 26;
    int r = r0 + rr;
    uint32_t c0 = jax_col(0, (uint32_t)r);
    int s1 = adj[(size_t)batch[r / S2N] * MAX_DEG + c0];
    if (t < 25) {
      uint32_t col = jax_col(1, (uint32_t)(r * S1N + t));
      nbr[rr][t] = adj[(size_t)s1 * MAX_DEG + col];
    } else {
      nbr[rr][25] = s1;
    }
  }
  __syncthreads();

  // ---- gather: 16 groups of 32 lanes; 4 floats/lane per source row ----
  {
    const int g = tid >> 5, lane = tid & 31;
    const int rr = g >> 1, hf = g & 1;
    const int k0 = hf * 128 + lane * 4;
    float4 a = make_float4(0.f, 0.f, 0.f, 0.f);
#pragma unroll 5
    for (int t = 0; t < 25; ++t) {
      const float4 v =
          *reinterpret_cast<const float4*>(&feat[(size_t)nbr[rr][t] * F_DIM + k0]);
      a.x += v.x; a.y += v.y; a.z += v.z; a.w += v.w;
    }
    const float4 s =
        *reinterpret_cast<const float4*>(&feat[(size_t)nbr[rr][25] * F_DIM + k0]);

    // self half to global for k_tail's h0-neighbor-mean
    *reinterpret_cast<float4*>(&Xself[(size_t)(r0 + rr) * 256 + k0]) = s;

    // transposed LDS store (one-time; write conflicts known & tolerated)
    const int G = rr >> 2, rl = rr & 3;
    const float inv = 1.f / (float)S1N;
    xl[G][k0 + 0][rl] = s.x;  xl[G][k0 + 1][rl] = s.y;
    xl[G][k0 + 2][rl] = s.z;  xl[G][k0 + 3][rl] = s.w;
    xl[G][256 + k0 + 0][rl] = a.x * inv; xl[G][256 + k0 + 1][rl] = a.y * inv;
    xl[G][256 + k0 + 2][rl] = a.z * inv; xl[G][256 + k0 + 3][rl] = a.w * inv;
  }
  __syncthreads();

  // ---- mm phase (same math as verified r6/r8; 4 rows per thread) ----
  const int j = tid & (H_DIM - 1);
  const int h = (tid >> 7) & 1;                    // 0: self@Ws, 1: mean@Wn
  const int q = tid >> 8;                          // row group: 0 -> 0-3, 1 -> 4-7
  const float* __restrict__ W = h ? Wn : Ws;
  float acc[4] = {0.f, 0.f, 0.f, 0.f};

#pragma unroll 4
  for (int k = 0; k < F_DIM; ++k) {
    float w = W[k * H_DIM + j];
    int kk = (h << 8) + k;
    float4 xa = *reinterpret_cast<const float4*>(&xl[q][kk][0]);
    acc[0] += xa.x * w; acc[1] += xa.y * w; acc[2] += xa.z * w; acc[3] += xa.w * w;
  }
#pragma unroll
  for (int i = 0; i < 4; ++i)
    h1out[(size_t)(r0 + q * 4 + i) * 256 + (h << 7) + j] = fmaxf(acc[i], 0.f);
}

// ---------------------------------------------------------------------------
// K2 (fused h0 + out): per batch row b (grid 512, 256 thr). Unchanged (verified).
__global__ __launch_bounds__(256) void k_tail(const float* __restrict__ feat,
                                              const int* __restrict__ batch,
                                              const float* __restrict__ Xself,
                                              const float* __restrict__ h1out,
                                              const float* __restrict__ Ws0,
                                              const float* __restrict__ Wn0,
                                              const float* __restrict__ Ws1,
                                              const float* __restrict__ Wn1,
                                              float* __restrict__ out) {
  __shared__ float sA[2][F_DIM];
  __shared__ float sB[2][F_DIM];
  __shared__ float red[4];
  const int tid = threadIdx.x;
  const int b = blockIdx.x;
  const int j = tid & (H_DIM - 1);
  const int h = tid >> 7;

  {
    float m = 0.f;
#pragma unroll
    for (int t = 0; t < S2N; ++t)
      m += Xself[(size_t)(b * S2N + t) * 256 + tid];
    sA[1][tid] = m / (float)S2N;
    sA[0][tid] = feat[(size_t)batch[b] * F_DIM + tid];
  }
  __syncthreads();

  const float* __restrict__ W0 = h ? Wn0 : Ws0;
  float a0 = 0.f;
#pragma unroll 4
  for (int k4 = 0; k4 < F_DIM / 4; ++k4) {
    float4 s4 = *reinterpret_cast<const float4*>(&sA[h][k4 * 4]);
    a0 += s4.x * W0[(k4 * 4 + 0) * H_DIM + j];
    a0 += s4.y * W0[(k4 * 4 + 1) * H_DIM + j];
    a0 += s4.z * W0[(k4 * 4 + 2) * H_DIM + j];
    a0 += s4.w * W0[(k4 * 4 + 3) * H_DIM + j];
  }
  a0 = fmaxf(a0, 0.f);

  sB[0][tid] = a0;
  {
    float m = 0.f;
#pragma unroll
    for (int t = 0; t < S2N; ++t)
      m += h1out[(size_t)(b * S2N + t) * 256 + tid];
    sB[1][tid] = m / (float)S2N;
  }
  __syncthreads();

  const float* __restrict__ W1 = h ? Wn1 : Ws1;
  float a1 = 0.f;
#pragma unroll 4
  for (int k4 = 0; k4 < F_DIM / 4; ++k4) {
    float4 s4 = *reinterpret_cast<const float4*>(&sB[h][k4 * 4]);
    a1 += s4.x * W1[(k4 * 4 + 0) * H_DIM + j];
    a1 += s4.y * W1[(k4 * 4 + 1) * H_DIM + j];
    a1 += s4.z * W1[(k4 * 4 + 2) * H_DIM + j];
    a1 += s4.w * W1[(k4 * 4 + 3) * H_DIM + j];
  }

  float s = a1 * a1;
#pragma unroll
  for (int off = 32; off > 0; off >>= 1) s += __shfl_xor(s, off);
  if ((tid & 63) == 0) red[tid >> 6] = s;
  __syncthreads();
  float tot = red[0] + red[1] + red[2] + red[3];
  float inv = 1.f / fmaxf(sqrtf(tot), 1e-12f);
  out[(size_t)b * 256 + tid] = a1 * inv;
}

// ---------------------------------------------------------------------------
extern "C" void kernel_launch(void* const* d_in, const int* in_sizes, int n_in,
                              void* d_out, int out_size, void* d_ws, size_t ws_size,
                              hipStream_t stream) {
  const float* feat  = (const float*)d_in[0];
  const int*   adj   = (const int*)d_in[1];
  const int*   batch = (const int*)d_in[2];
  const float* Ws0   = (const float*)d_in[3];
  const float* Wn0   = (const float*)d_in[4];
  const float* Ws1   = (const float*)d_in[5];
  const float* Wn1   = (const float*)d_in[6];
  float* out = (float*)d_out;

  char* ws = (char*)d_ws;
  float* Xself = (float*)(ws);                    // 5120*256*4 = 5.25 MB
  float* h1out = (float*)(ws + (8u << 20));       // 5120*256*4 = 5.25 MB

  k_gmm <<<NS1 / RMM, 512, 0, stream>>>(feat, adj, batch, Ws0, Wn0, Xself, h1out);
  k_tail<<<BATCH, 256, 0, stream>>>(feat, batch, Xself, h1out, Ws0, Wn0, Ws1, Wn1, out);
}

// Round 10
// 53.651 us; speedup vs baseline: 1.4375x; 1.0103x over previous
//
#include <hip/hip_runtime.h>
#include <stdint.h>

// ---------------------------------------------------------------------------
// GraphSAGE SampleAndAggregate — RNG VERIFIED (round 5, variant 5):
//   modern JAX: partitionable threefry, foldlike split, and randint's
//   INTERNAL k1,k2=split(key); col_i = (x0^x1)(tf(tf(key,(0,1)),(0,i))) & 127
// DO NOT change the RNG path.
// ---------------------------------------------------------------------------
#define N_NODES 100000
#define F_DIM   256
#define H_DIM   128
#define MAX_DEG 128
#define BATCH   512
#define S1N     25
#define S2N     10
#define NS1     (BATCH * S2N)   // 5120
#define NS2     (NS1 * S1N)     // 128000

__device__ __forceinline__ void tf2(uint32_t k0, uint32_t k1, uint32_t c0, uint32_t c1,
                                    uint32_t& o0, uint32_t& o1) {
  uint32_t ks0 = k0, ks1 = k1, ks2 = k0 ^ k1 ^ 0x1BD11BDAu;
  uint32_t x0 = c0 + ks0;
  uint32_t x1 = c1 + ks1;
#define TF_ROUND(r) { x0 += x1; x1 = (x1 << (r)) | (x1 >> (32 - (r))); x1 ^= x0; }
  TF_ROUND(13); TF_ROUND(15); TF_ROUND(26); TF_ROUND(6);
  x0 += ks1; x1 += ks2 + 1u;
  TF_ROUND(17); TF_ROUND(29); TF_ROUND(16); TF_ROUND(24);
  x0 += ks2; x1 += ks0 + 2u;
  TF_ROUND(13); TF_ROUND(15); TF_ROUND(26); TF_ROUND(6);
  x0 += ks0; x1 += ks1 + 3u;
  TF_ROUND(17); TF_ROUND(29); TF_ROUND(16); TF_ROUND(24);
  x0 += ks1; x1 += ks2 + 4u;
  TF_ROUND(13); TF_ROUND(15); TF_ROUND(26); TF_ROUND(6);
  x0 += ks2; x1 += ks0 + 5u;
#undef TF_ROUND
  o0 = x0; o1 = x1;
}

// col draw i of randint(subkey_idx, ..., 0, 128) under verified semantics
__device__ __forceinline__ uint32_t jax_col(int subkey_idx, uint32_t i) {
  uint32_t k0, k1, kk0, kk1, o0, o1;
  tf2(0u, 42u, 0u, (uint32_t)subkey_idx, k0, k1);  // foldlike split of key(42)
  tf2(k0, k1, 0u, 1u, kk0, kk1);                   // randint internal k2
  tf2(kk0, kk1, 0u, i, o0, o1);                    // lower_bits draw i
  return (o0 ^ o1) & (MAX_DEG - 1);
}

// ---------------------------------------------------------------------------
// K1 (fused sample + gather + layer-0 matmul for the 5120 h1 rows).
// Grid 640, block 512. Wave w (of 8) owns s1-row r0+w:
//   gather: 64 lanes x float4 = full 1-KB row per wave-load; source indices
//           hoisted to SGPRs (readfirstlane) -> saddr loads; 5 independent
//           accumulators + full unroll for deep MLP.
//   mm:     thread (q=tid>>8, h, j) computes rows q*4..q*4+3, col h*128+j
#define RMM 8
__global__ __launch_bounds__(512, 1) void k_gmm(const float* __restrict__ feat,
                                                const int* __restrict__ adj,
                                                const int* __restrict__ batch,
                                                const float* __restrict__ Ws,
                                                const float* __restrict__ Wn,
                                                float* __restrict__ Xself,
                                                float* __restrict__ h1out) {
  __shared__ int   nbr[RMM][26];    // [.][25] = self (s1)
  __shared__ float xl[2][512][4];   // 16 KB, transposed X tile
  const int tid = threadIdx.x;
  const int r0 = blockIdx.x * RMM;

  if (tid < RMM * 26) {
    int rr = tid / 26, t = tid % 26;
    int r = r0 + rr;
    uint32_t c0 = jax_col(0, (uint32_t)r);
    int s1 = adj[(size_t)batch[r / S2N] * MAX_DEG + c0];
    if (t < 25) {
      uint32_t col = jax_col(1, (uint32_t)(r * S1N + t));
      nbr[rr][t] = adj[(size_t)s1 * MAX_DEG + col];
    } else {
      nbr[rr][25] = s1;
    }
  }
  __syncthreads();

  // ---- gather: wave w -> row w; deep memory-level parallelism ----
  {
    const int w = tid >> 6, lane = tid & 63;
    const int k0 = lane * 4;

    // wave-uniform source ids -> scalar registers (saddr-form loads)
    int idx[26];
#pragma unroll
    for (int t = 0; t < 26; ++t)
      idx[t] = __builtin_amdgcn_readfirstlane(nbr[w][t]);

    float4 acc[5];
#pragma unroll
    for (int i = 0; i < 5; ++i) acc[i] = make_float4(0.f, 0.f, 0.f, 0.f);

#pragma unroll
    for (int t = 0; t < 25; ++t) {
      const float4 v =
          *reinterpret_cast<const float4*>(&feat[(size_t)idx[t] * F_DIM + k0]);
      acc[t % 5].x += v.x; acc[t % 5].y += v.y;
      acc[t % 5].z += v.z; acc[t % 5].w += v.w;
    }
    const float4 s =
        *reinterpret_cast<const float4*>(&feat[(size_t)idx[25] * F_DIM + k0]);

    float4 a;
    a.x = ((acc[0].x + acc[1].x) + (acc[2].x + acc[3].x)) + acc[4].x;
    a.y = ((acc[0].y + acc[1].y) + (acc[2].y + acc[3].y)) + acc[4].y;
    a.z = ((acc[0].z + acc[1].z) + (acc[2].z + acc[3].z)) + acc[4].z;
    a.w = ((acc[0].w + acc[1].w) + (acc[2].w + acc[3].w)) + acc[4].w;

    // self half to global for k_tail's h0-neighbor-mean
    *reinterpret_cast<float4*>(&Xself[(size_t)(r0 + w) * 256 + k0]) = s;

    // transposed LDS store (one-time; write conflicts known & tolerated)
    const int G = w >> 2, rl = w & 3;
    const float inv = 1.f / (float)S1N;
    xl[G][k0 + 0][rl] = s.x;  xl[G][k0 + 1][rl] = s.y;
    xl[G][k0 + 2][rl] = s.z;  xl[G][k0 + 3][rl] = s.w;
    xl[G][256 + k0 + 0][rl] = a.x * inv; xl[G][256 + k0 + 1][rl] = a.y * inv;
    xl[G][256 + k0 + 2][rl] = a.z * inv; xl[G][256 + k0 + 3][rl] = a.w * inv;
  }
  __syncthreads();

  // ---- mm phase (same math as verified r6/r8; 4 rows per thread) ----
  const int j = tid & (H_DIM - 1);
  const int h = (tid >> 7) & 1;                    // 0: self@Ws, 1: mean@Wn
  const int q = tid >> 8;                          // row group: 0 -> 0-3, 1 -> 4-7
  const float* __restrict__ W = h ? Wn : Ws;
  float acc[4] = {0.f, 0.f, 0.f, 0.f};

#pragma unroll 4
  for (int k = 0; k < F_DIM; ++k) {
    float w = W[k * H_DIM + j];
    int kk = (h << 8) + k;
    float4 xa = *reinterpret_cast<const float4*>(&xl[q][kk][0]);
    acc[0] += xa.x * w; acc[1] += xa.y * w; acc[2] += xa.z * w; acc[3] += xa.w * w;
  }
#pragma unroll
  for (int i = 0; i < 4; ++i)
    h1out[(size_t)(r0 + q * 4 + i) * 256 + (h << 7) + j] = fmaxf(acc[i], 0.f);
}

// ---------------------------------------------------------------------------
// K2 (fused h0 + out): per batch row b (grid 512, 256 thr). Unchanged (verified).
__global__ __launch_bounds__(256) void k_tail(const float* __restrict__ feat,
                                              const int* __restrict__ batch,
                                              const float* __restrict__ Xself,
                                              const float* __restrict__ h1out,
                                              const float* __restrict__ Ws0,
                                              const float* __restrict__ Wn0,
                                              const float* __restrict__ Ws1,
                                              const float* __restrict__ Wn1,
                                              float* __restrict__ out) {
  __shared__ float sA[2][F_DIM];
  __shared__ float sB[2][F_DIM];
  __shared__ float red[4];
  const int tid = threadIdx.x;
  const int b = blockIdx.x;
  const int j = tid & (H_DIM - 1);
  const int h = tid >> 7;

  {
    float m = 0.f;
#pragma unroll
    for (int t = 0; t < S2N; ++t)
      m += Xself[(size_t)(b * S2N + t) * 256 + tid];
    sA[1][tid] = m / (float)S2N;
    sA[0][tid] = feat[(size_t)batch[b] * F_DIM + tid];
  }
  __syncthreads();

  const float* __restrict__ W0 = h ? Wn0 : Ws0;
  float a0 = 0.f;
#pragma unroll 4
  for (int k4 = 0; k4 < F_DIM / 4; ++k4) {
    float4 s4 = *reinterpret_cast<const float4*>(&sA[h][k4 * 4]);
    a0 += s4.x * W0[(k4 * 4 + 0) * H_DIM + j];
    a0 += s4.y * W0[(k4 * 4 + 1) * H_DIM + j];
    a0 += s4.z * W0[(k4 * 4 + 2) * H_DIM + j];
    a0 += s4.w * W0[(k4 * 4 + 3) * H_DIM + j];
  }
  a0 = fmaxf(a0, 0.f);

  sB[0][tid] = a0;
  {
    float m = 0.f;
#pragma unroll
    for (int t = 0; t < S2N; ++t)
      m += h1out[(size_t)(b * S2N + t) * 256 + tid];
    sB[1][tid] = m / (float)S2N;
  }
  __syncthreads();

  const float* __restrict__ W1 = h ? Wn1 : Ws1;
  float a1 = 0.f;
#pragma unroll 4
  for (int k4 = 0; k4 < F_DIM / 4; ++k4) {
    float4 s4 = *reinterpret_cast<const float4*>(&sB[h][k4 * 4]);
    a1 += s4.x * W1[(k4 * 4 + 0) * H_DIM + j];
    a1 += s4.y * W1[(k4 * 4 + 1) * H_DIM + j];
    a1 += s4.z * W1[(k4 * 4 + 2) * H_DIM + j];
    a1 += s4.w * W1[(k4 * 4 + 3) * H_DIM + j];
  }

  float s = a1 * a1;
#pragma unroll
  for (int off = 32; off > 0; off >>= 1) s += __shfl_xor(s, off);
  if ((tid & 63) == 0) red[tid >> 6] = s;
  __syncthreads();
  float tot = red[0] + red[1] + red[2] + red[3];
  float inv = 1.f / fmaxf(sqrtf(tot), 1e-12f);
  out[(size_t)b * 256 + tid] = a1 * inv;
}

// ---------------------------------------------------------------------------
extern "C" void kernel_launch(void* const* d_in, const int* in_sizes, int n_in,
                              void* d_out, int out_size, void* d_ws, size_t ws_size,
                              hipStream_t stream) {
  const float* feat  = (const float*)d_in[0];
  const int*   adj   = (const int*)d_in[1];
  const int*   batch = (const int*)d_in[2];
  const float* Ws0   = (const float*)d_in[3];
  const float* Wn0   = (const float*)d_in[4];
  const float* Ws1   = (const float*)d_in[5];
  const float* Wn1   = (const float*)d_in[6];
  float* out = (float*)d_out;

  char* ws = (char*)d_ws;
  float* Xself = (float*)(ws);                    // 5120*256*4 = 5.25 MB
  float* h1out = (float*)(ws + (8u << 20));       // 5120*256*4 = 5.25 MB

  k_gmm <<<NS1 / RMM, 512, 0, stream>>>(feat, adj, batch, Ws0, Wn0, Xself, h1out);
  k_tail<<<BATCH, 256, 0, stream>>>(feat, batch, Xself, h1out, Ws0, Wn0, Ws1, Wn1, out);
}